// Round 5
// baseline (197.701 us; speedup 1.0000x reference)
//
#include <hip/hip_runtime.h>
#include <hip/hip_bf16.h>

#define TPB 256
#define NEXPERT 64
#define CHUNK 256            // == TPB; one chunk per block in phases 1 & 3
#define GRID 512             // 2 blocks/CU needed co-resident; capacity >= 4

typedef float f32x4 __attribute__((ext_vector_type(4)));

// ---------------------------------------------------------------------------
// Software grid barrier (persistent-grid pattern). One atomic per block per
// phase; agent-scope acq_rel gives cross-XCD visibility of prior writes.
// Bounded spin: on pathological non-residency we terminate (and fail
// validation loudly) instead of hanging the harness.
// ---------------------------------------------------------------------------
__device__ __forceinline__ void grid_barrier(unsigned* bar, unsigned target) {
    __syncthreads();
    if (threadIdx.x == 0) {
        __hip_atomic_fetch_add(bar, 1u, __ATOMIC_ACQ_REL, __HIP_MEMORY_SCOPE_AGENT);
        long long guard = 0;
        while (__hip_atomic_load(bar, __ATOMIC_ACQUIRE,
                                 __HIP_MEMORY_SCOPE_AGENT) < target) {
            __builtin_amdgcn_s_sleep(4);
            if (++guard > (1LL << 22)) break;  // safety valve: fail, don't hang
        }
    }
    __syncthreads();
}

// ---------------------------------------------------------------------------
// One persistent kernel, 4 phases (R2's proven per-phase logic):
//  P1 blocks 0..NB-1: per-chunk 64-bin histogram -> counts[e*NB + c]
//  P2 block 0:        exclusive scan of counts (shfl scan + expert bases)
//  P3 blocks 0..NB-1: stable ballot scatter -> out_row / out_expert
//  P4 all blocks:     token-driven gather, 16 contiguous tokens each,
//                     plain f32x4 loads + nontemporal stores.
// Stable order = (expert, chunk, in-chunk pos) == stable argsort by expert.
// Row values are arange(N*K) (so token of flat i is i % N) — same assumption
// all previous passing rounds relied on.
// KT > 0: compile-time K fast path. KT == 0: runtime-K per-k passes.
// ---------------------------------------------------------------------------
template <int KT>
__global__ __launch_bounds__(TPB, 4) void k_all(
    const float* __restrict__ x, const int* __restrict__ expert,
    unsigned* __restrict__ bar, int* __restrict__ counts,
    float* __restrict__ out_x, float* __restrict__ out_row,
    float* __restrict__ out_expert, int H, int N, int NK, int NB, int Kdyn) {
    __shared__ int h[NEXPERT];
    __shared__ int wcnt[TPB / 64][NEXPERT + 1];
    __shared__ int etot[NEXPERT], ebase[NEXPERT];
    const int tid = threadIdx.x;
    const int bid = blockIdx.x;
    const int w = tid >> 6, lane = tid & 63;

    // ---- Phase 1: per-chunk histogram ----
    if (bid < NB) {
        if (tid < NEXPERT) h[tid] = 0;
        __syncthreads();
        const int i = bid * CHUNK + tid;
        if (i < NK) atomicAdd(&h[expert[i]], 1);
        __syncthreads();
        if (tid < NEXPERT) counts[tid * NB + bid] = h[tid];
    }
    grid_barrier(bar, GRID);

    // ---- Phase 2: exclusive scan over NEXPERT*NB counts (block 0) ----
    if (bid == 0) {
        for (int e = w; e < NEXPERT; e += TPB / 64) {
            int carry = 0;
            for (int cb = 0; cb < NB; cb += 64) {
                const int c = cb + lane;
                const int v = (c < NB) ? counts[e * NB + c] : 0;
                int incl = v;
#pragma unroll
                for (int off = 1; off < 64; off <<= 1) {
                    const int u = __shfl_up(incl, off, 64);
                    if (lane >= off) incl += u;
                }
                if (c < NB) counts[e * NB + c] = carry + incl - v;
                carry += __shfl(incl, 63, 64);
            }
            if (lane == 0) etot[e] = carry;
        }
        __syncthreads();
        if (w == 0) {
            const int v = etot[lane];
            int incl = v;
#pragma unroll
            for (int off = 1; off < 64; off <<= 1) {
                const int u = __shfl_up(incl, off, 64);
                if (lane >= off) incl += u;
            }
            ebase[lane] = incl - v;
        }
        __syncthreads();
        for (int e = w; e < NEXPERT; e += TPB / 64) {
            const int b = ebase[e];
            for (int c = lane; c < NB; c += 64) counts[e * NB + c] += b;
        }
    }
    grid_barrier(bar, 2u * GRID);

    // ---- Phase 3: stable ballot scatter ----
    if (bid < NB) {
        const int i = bid * CHUNK + tid;
        const bool valid = (i < NK);
        const int e = valid ? expert[i] : NEXPERT;   // sentinel
        for (int idx = tid; idx < (TPB / 64) * (NEXPERT + 1); idx += TPB)
            (&wcnt[0][0])[idx] = 0;
        __syncthreads();
        unsigned long long mask = ~0ull;
#pragma unroll
        for (int bit = 0; bit < 7; ++bit) {
            const unsigned long long bv = __ballot((e >> bit) & 1);
            mask &= ((e >> bit) & 1) ? bv : ~bv;
        }
        const int rank_w = __popcll(mask & ((1ull << lane) - 1ull));
        if (valid && rank_w == 0) wcnt[w][e] = __popcll(mask);
        __syncthreads();
        if (valid) {
            int rank = rank_w;
            for (int w2 = 0; w2 < w; ++w2) rank += wcnt[w2][e];
            const int dst = counts[e * NB + bid] + rank;
            out_row[i] = (float)dst;          // row values are arange
            out_expert[dst] = (float)e;
        }
    }
    grid_barrier(bar, 3u * GRID);

    // ---- Phase 4: token-driven gather ----
    const int TOK = (N + GRID - 1) / GRID;
    const int tstart = bid * TOK;
    const int tend = (tstart + TOK < N) ? (tstart + TOK) : N;
    const int n4 = H >> 2;
    if (KT > 0) {
        for (int t = tstart; t < tend; ++t) {
            size_t ob[KT > 0 ? KT : 1];
#pragma unroll
            for (int kk = 0; kk < KT; ++kk)
                ob[kk] = (size_t)(int)out_row[t + kk * N] * (size_t)H;
            const f32x4* __restrict__ src =
                (const f32x4*)(x + (size_t)t * (size_t)H);
            for (int j = tid; j < n4; j += TPB) {
                const f32x4 v = src[j];
#pragma unroll
                for (int kk = 0; kk < KT; ++kk)
                    __builtin_nontemporal_store(v, (f32x4*)(out_x + ob[kk]) + j);
            }
        }
    } else {
        for (int t = tstart; t < tend; ++t) {
            const f32x4* __restrict__ src =
                (const f32x4*)(x + (size_t)t * (size_t)H);
            for (int kk = 0; kk < Kdyn; ++kk) {
                const size_t ob = (size_t)(int)out_row[t + kk * N] * (size_t)H;
                for (int j = tid; j < n4; j += TPB)
                    __builtin_nontemporal_store(src[j], (f32x4*)(out_x + ob) + j);
            }
        }
    }
}

extern "C" void kernel_launch(void* const* d_in, const int* in_sizes, int n_in,
                              void* d_out, int out_size, void* d_ws, size_t ws_size,
                              hipStream_t stream) {
    const float* x    = (const float*)d_in[0];  // [N, H] fp32
    const int*   expi = (const int*)d_in[2];    // [N, K] int32

    const int NK = in_sizes[1];                    // N*K = 16384
    const int H  = (out_size - 2 * NK) / NK;       // 4096
    const int N  = in_sizes[0] / H;                // 8192
    const int K  = NK / N;                         // 2
    const int NB = (NK + CHUNK - 1) / CHUNK;       // 64 chunks

    // Output layout (all float32): [NK*H] expanded_x | [NK] row_idx | [NK] expert_idx
    float* out_x      = (float*)d_out;
    float* out_row    = out_x + (size_t)NK * (size_t)H;
    float* out_expert = out_row + NK;

    // Workspace: [0] barrier counter | +64 ints: scanned counts [64*NB]
    unsigned* bar = (unsigned*)d_ws;
    int* counts   = (int*)d_ws + 64;

    hipMemsetAsync(bar, 0, sizeof(unsigned), stream);

    switch (K) {
        case 1: k_all<1><<<GRID, TPB, 0, stream>>>(x, expi, bar, counts, out_x, out_row, out_expert, H, N, NK, NB, K); break;
        case 2: k_all<2><<<GRID, TPB, 0, stream>>>(x, expi, bar, counts, out_x, out_row, out_expert, H, N, NK, NB, K); break;
        case 3: k_all<3><<<GRID, TPB, 0, stream>>>(x, expi, bar, counts, out_x, out_row, out_expert, H, N, NK, NB, K); break;
        case 4: k_all<4><<<GRID, TPB, 0, stream>>>(x, expi, bar, counts, out_x, out_row, out_expert, H, N, NK, NB, K); break;
        default: k_all<0><<<GRID, TPB, 0, stream>>>(x, expi, bar, counts, out_x, out_row, out_expert, H, N, NK, NB, K); break;
    }
}

// Round 6
// 96.693 us; speedup vs baseline: 2.0446x; 2.0446x over previous
//
#include <hip/hip_runtime.h>
#include <hip/hip_bf16.h>

#define TPB 256
#define NEXPERT 64
#define CHUNK 256            // one chunk per prelude block

typedef float f32x4 __attribute__((ext_vector_type(4)));

// ---------------------------------------------------------------------------
// K1: fully-parallel prelude, ONE dispatch, no cross-block dependency.
// Block b (of NB=NK/256) redundantly reads the WHOLE expert array (64 KB,
// L2-broadcast across blocks) and computes, independently:
//   hist[c][e]  — per-chunk 64-bin histograms (ballot-grouped, one LDS RMW
//                 per distinct expert per 64-lane pass; wave owns chunk ->
//                 no atomics; [c][e] layout keeps banks spread)
//   epre[e]     — sum of hist[c][e] for c < b   (prefix over chunks)
//   ebase[e]    — global exclusive scan of totals (wave-0 shfl scan)
// Then the proven ballot rank for its own chunk:
//   dst = ebase[e] + epre[e] + rank_in_chunk    (stable (e, i) order)
// Writes out_row[rowi[i]] = dst, out_expert[dst] = e, dst_of_r[rowi[i]] = dst.
// ---------------------------------------------------------------------------
__global__ __launch_bounds__(TPB) void k_prelude(
    const int* __restrict__ expert, const int* __restrict__ rowi,
    int NK, int NB,
    float* __restrict__ out_row, float* __restrict__ out_expert,
    int* __restrict__ dst_of_r) {
    extern __shared__ int hist[];            // [NB][NEXPERT]
    __shared__ int wcnt[TPB / 64][NEXPERT + 1];
    __shared__ int ebase[NEXPERT], epre[NEXPERT];
    const int tid = threadIdx.x;
    const int b = blockIdx.x;
    const int w = tid >> 6, lane = tid & 63;
    const int nw = TPB / 64;

    for (int idx = tid; idx < NB * NEXPERT; idx += TPB) hist[idx] = 0;
    __syncthreads();

    // ---- per-chunk histograms over the WHOLE array (wave w owns chunks
    //      c = w, w+nw, ...) ----
    for (int c = w; c < NB; c += nw) {
#pragma unroll
        for (int p = 0; p < CHUNK / 64; ++p) {
            const int idx = c * CHUNK + p * 64 + lane;
            const bool valid = (idx < NK);
            const int e = valid ? expert[idx] : NEXPERT;  // sentinel
            unsigned long long mask = ~0ull;
#pragma unroll
            for (int bit = 0; bit < 7; ++bit) {
                const unsigned long long bv = __ballot((e >> bit) & 1);
                mask &= ((e >> bit) & 1) ? bv : ~bv;
            }
            const int rank_w = __popcll(mask & ((1ull << lane) - 1ull));
            if (valid && rank_w == 0) hist[c * NEXPERT + e] += __popcll(mask);
        }
    }
    __syncthreads();

    // ---- per-expert prefix (c < b) and global exclusive base (wave 0) ----
    if (tid < NEXPERT) {
        int pre = 0, tot = 0;
        for (int c = 0; c < NB; ++c) {
            const int v = hist[c * NEXPERT + tid];
            pre += (c < b) ? v : 0;
            tot += v;
        }
        int incl = tot;
#pragma unroll
        for (int off = 1; off < NEXPERT; off <<= 1) {
            const int u = __shfl_up(incl, off, 64);
            if (lane >= off) incl += u;
        }
        ebase[tid] = incl - tot;
        epre[tid] = pre;
    }

    // ---- stable rank for own chunk ----
    const int i = b * CHUNK + tid;
    const bool valid = (i < NK);
    const int e = valid ? expert[i] : NEXPERT;
    for (int idx = tid; idx < nw * (NEXPERT + 1); idx += TPB)
        (&wcnt[0][0])[idx] = 0;
    __syncthreads();

    unsigned long long mask = ~0ull;
#pragma unroll
    for (int bit = 0; bit < 7; ++bit) {
        const unsigned long long bv = __ballot((e >> bit) & 1);
        mask &= ((e >> bit) & 1) ? bv : ~bv;
    }
    const int rank_w = __popcll(mask & ((1ull << lane) - 1ull));
    if (valid && rank_w == 0) wcnt[w][e] = __popcll(mask);
    __syncthreads();

    if (valid) {
        int rank = rank_w;
        for (int w2 = 0; w2 < w; ++w2) rank += wcnt[w2][e];
        const int dst = ebase[e] + epre[e] + rank;
        const int r = rowi[i];
        out_row[r] = (float)dst;
        out_expert[dst] = (float)e;
        dst_of_r[r] = dst;
    }
}

// ---------------------------------------------------------------------------
// K2: token-driven gather (byte-identical structure to the 77 µs R2 winner).
// Token t is consumed by exactly the row VALUES {t, t+N, ...} (reference
// gathers x[r % N]; row values are arange). Read x[t] ONCE (plain loads —
// x is ~50% L3-resident, measured FETCH 65.7 MB < 134 MB), write to all K
// destinations with nontemporal float4 stores.
// ---------------------------------------------------------------------------
template <int K>
__global__ __launch_bounds__(TPB) void k_gatherT(
    const float* __restrict__ x, const int* __restrict__ dst_of_r,
    float* __restrict__ out_x, int H, int N) {
    const int t = blockIdx.x;
    const f32x4* __restrict__ src = (const f32x4*)(x + (size_t)t * (size_t)H);
    size_t ob[K];
#pragma unroll
    for (int kk = 0; kk < K; ++kk)
        ob[kk] = (size_t)dst_of_r[t + kk * N] * (size_t)H;
    const int n4 = H >> 2;
    for (int j = threadIdx.x; j < n4; j += blockDim.x) {
        const f32x4 v = src[j];
#pragma unroll
        for (int kk = 0; kk < K; ++kk)
            __builtin_nontemporal_store(v, (f32x4*)(out_x + ob[kk]) + j);
    }
}

// Generic-K fallback (one pass per k; only used for K > 4)
__global__ void k_gather_gen(const float* __restrict__ x,
                             const int* __restrict__ dst_of_r,
                             float* __restrict__ out_x, int H, int N, int K) {
    const int t = blockIdx.x;
    const f32x4* __restrict__ src = (const f32x4*)(x + (size_t)t * (size_t)H);
    const int n4 = H >> 2;
    for (int kk = 0; kk < K; ++kk) {
        const size_t ob = (size_t)dst_of_r[t + kk * N] * (size_t)H;
        for (int j = threadIdx.x; j < n4; j += blockDim.x)
            __builtin_nontemporal_store(src[j], (f32x4*)(out_x + ob) + j);
    }
}

extern "C" void kernel_launch(void* const* d_in, const int* in_sizes, int n_in,
                              void* d_out, int out_size, void* d_ws, size_t ws_size,
                              hipStream_t stream) {
    const float* x    = (const float*)d_in[0];  // [N, H] fp32
    const int*   rowi = (const int*)d_in[1];    // [N, K] int32 (arange values)
    const int*   expi = (const int*)d_in[2];    // [N, K] int32

    const int NK = in_sizes[1];                    // N*K = 16384
    const int H  = (out_size - 2 * NK) / NK;       // 4096
    const int N  = in_sizes[0] / H;                // 8192
    const int K  = NK / N;                         // 2
    const int NB = (NK + CHUNK - 1) / CHUNK;       // 64 chunks

    // Output layout (all float32): [NK*H] expanded_x | [NK] row_idx | [NK] expert_idx
    float* out_x      = (float*)d_out;
    float* out_row    = out_x + (size_t)NK * (size_t)H;
    float* out_expert = out_row + NK;

    int* dst_of_r = (int*)d_ws;

    const size_t lds_bytes = (size_t)NB * NEXPERT * sizeof(int);
    k_prelude<<<NB, TPB, lds_bytes, stream>>>(expi, rowi, NK, NB,
                                              out_row, out_expert, dst_of_r);

    switch (K) {
        case 1: k_gatherT<1><<<N, TPB, 0, stream>>>(x, dst_of_r, out_x, H, N); break;
        case 2: k_gatherT<2><<<N, TPB, 0, stream>>>(x, dst_of_r, out_x, H, N); break;
        case 3: k_gatherT<3><<<N, TPB, 0, stream>>>(x, dst_of_r, out_x, H, N); break;
        case 4: k_gatherT<4><<<N, TPB, 0, stream>>>(x, dst_of_r, out_x, H, N); break;
        default: k_gather_gen<<<N, TPB, 0, stream>>>(x, dst_of_r, out_x, H, N, K); break;
    }
}

// Round 7
// 77.616 us; speedup vs baseline: 2.5472x; 1.2458x over previous
//
#include <hip/hip_runtime.h>
#include <hip/hip_bf16.h>

#define TPB 256
#define NEXPERT 64

typedef float f32x4 __attribute__((ext_vector_type(4)));

// ---------------------------------------------------------------------------
// REPLICATION RUN: byte-for-byte the Round-2 kernel (77.1 µs) to A/B against
// R6 (96.7 µs). No changes. If this reproduces ~77, R2's structure is real;
// if it lands ~95-100, the band is measurement noise and we're at the wall.
// ---------------------------------------------------------------------------

// K1: per-chunk expert histogram. counts[e * NB + b] layout so a flat
// exclusive scan yields stable counting-sort bases.
__global__ void k_hist(const int* __restrict__ expert, int NK, int NB,
                       int* __restrict__ counts) {
    __shared__ int h[NEXPERT];
    const int b = blockIdx.x;
    for (int e = threadIdx.x; e < NEXPERT; e += blockDim.x) h[e] = 0;
    __syncthreads();
    const int i = b * TPB + threadIdx.x;
    if (i < NK) atomicAdd(&h[expert[i]], 1);
    __syncthreads();
    for (int e = threadIdx.x; e < NEXPERT; e += blockDim.x)
        counts[e * NB + b] = h[e];
}

// K2: single-block exclusive prefix scan over M = NEXPERT*NB ints (M=4096).
__global__ void k_scan(int* __restrict__ counts, int M) {
    __shared__ int s[1024];
    const int t = threadIdx.x;
    const int nt = blockDim.x;
    const int ipt = (M + nt - 1) / nt;      // elements per thread (4 here)
    int v[8];                               // ipt <= 8 assumed
    int sum = 0;
    for (int j = 0; j < ipt; ++j) {
        const int idx = t * ipt + j;
        v[j] = (idx < M) ? counts[idx] : 0;
        sum += v[j];
    }
    s[t] = sum;
    __syncthreads();
    for (int off = 1; off < nt; off <<= 1) {
        const int x = (t >= off) ? s[t - off] : 0;
        __syncthreads();
        s[t] += x;
        __syncthreads();
    }
    int base = (t == 0) ? 0 : s[t - 1];     // exclusive base for this thread
    for (int j = 0; j < ipt; ++j) {
        const int idx = t * ipt + j;
        const int c = v[j];
        if (idx < M) counts[idx] = base;
        base += c;
    }
}

// K3: stable scatter with ballot-based rank.
__global__ void k_scatter(const int* __restrict__ expert,
                          const int* __restrict__ rowi,
                          int NK, int NB,
                          const int* __restrict__ base,
                          float* __restrict__ out_row,
                          float* __restrict__ out_expert,
                          int* __restrict__ dst_of_r) {
    __shared__ int h[TPB / 64][NEXPERT + 1];
    const int b = blockIdx.x;
    const int tid = threadIdx.x;
    const int w = tid >> 6;
    const int lane = tid & 63;
    const int i = b * TPB + tid;
    const bool valid = (i < NK);
    const int e = valid ? expert[i] : NEXPERT;   // sentinel for inactive lanes

    for (int idx = tid; idx < (TPB / 64) * (NEXPERT + 1); idx += TPB)
        (&h[0][0])[idx] = 0;
    __syncthreads();

    unsigned long long mask = ~0ull;
#pragma unroll
    for (int bit = 0; bit < 7; ++bit) {
        const unsigned long long bv = __ballot((e >> bit) & 1);
        mask &= ((e >> bit) & 1) ? bv : ~bv;
    }
    const int rank_w = __popcll(mask & ((1ull << lane) - 1ull));
    const int cnt_w  = __popcll(mask);
    if (rank_w == 0) h[w][e] = cnt_w;   // lowest lane of each expert group
    __syncthreads();

    if (valid) {
        int rank = rank_w;
        for (int w2 = 0; w2 < w; ++w2) rank += h[w2][e];
        const int dst = base[e * NB + b] + rank;
        const int r = rowi[i];
        out_expert[dst] = (float)e;
        out_row[r] = (float)dst;
        dst_of_r[r] = dst;
    }
}

// K4: token-driven gather. Read x[t] once, write K destinations, NT stores.
template <int K>
__global__ void k_gatherT(const float* __restrict__ x,
                          const int* __restrict__ dst_of_r,
                          float* __restrict__ out_x, int H, int N) {
    const int t = blockIdx.x;
    const f32x4* __restrict__ src = (const f32x4*)(x + (size_t)t * (size_t)H);
    size_t ob[K];
#pragma unroll
    for (int kk = 0; kk < K; ++kk)
        ob[kk] = (size_t)dst_of_r[t + kk * N] * (size_t)H;
    const int n4 = H >> 2;
    for (int j = threadIdx.x; j < n4; j += blockDim.x) {
        const f32x4 v = src[j];
#pragma unroll
        for (int kk = 0; kk < K; ++kk)
            __builtin_nontemporal_store(v, (f32x4*)(out_x + ob[kk]) + j);
    }
}

// Generic-K fallback (only used for K > 4)
__global__ void k_gather_gen(const float* __restrict__ x,
                             const int* __restrict__ dst_of_r,
                             float* __restrict__ out_x, int H, int N, int K) {
    const int t = blockIdx.x;
    const f32x4* __restrict__ src = (const f32x4*)(x + (size_t)t * (size_t)H);
    const int n4 = H >> 2;
    for (int kk = 0; kk < K; ++kk) {
        const size_t ob = (size_t)dst_of_r[t + kk * N] * (size_t)H;
        for (int j = threadIdx.x; j < n4; j += blockDim.x)
            __builtin_nontemporal_store(src[j], (f32x4*)(out_x + ob) + j);
    }
}

extern "C" void kernel_launch(void* const* d_in, const int* in_sizes, int n_in,
                              void* d_out, int out_size, void* d_ws, size_t ws_size,
                              hipStream_t stream) {
    const float* x    = (const float*)d_in[0];  // [N, H] fp32
    const int*   rowi = (const int*)d_in[1];    // [N, K] int32 (arange)
    const int*   expi = (const int*)d_in[2];    // [N, K] int32

    const int NK = in_sizes[1];                    // N*K = 16384
    const int H  = (out_size - 2 * NK) / NK;       // 4096
    const int N  = in_sizes[0] / H;                // 8192
    const int K  = NK / N;                         // 2
    const int NB = (NK + TPB - 1) / TPB;           // 64 chunks

    // Output layout (all float32): [NK*H] expanded_x | [NK] row_idx | [NK] expert_idx
    float* out_x      = (float*)d_out;
    float* out_row    = out_x + (size_t)NK * (size_t)H;
    float* out_expert = out_row + NK;

    // Workspace: counts/bases [64*NB] ints, then dst_of_r [NK] ints.
    int* counts   = (int*)d_ws;
    int* dst_of_r = counts + NEXPERT * NB;

    k_hist   <<<NB, TPB, 0, stream>>>(expi, NK, NB, counts);
    k_scan   <<<1, 1024, 0, stream>>>(counts, NEXPERT * NB);
    k_scatter<<<NB, TPB, 0, stream>>>(expi, rowi, NK, NB, counts,
                                      out_row, out_expert, dst_of_r);

    switch (K) {
        case 1: k_gatherT<1><<<N, TPB, 0, stream>>>(x, dst_of_r, out_x, H, N); break;
        case 2: k_gatherT<2><<<N, TPB, 0, stream>>>(x, dst_of_r, out_x, H, N); break;
        case 3: k_gatherT<3><<<N, TPB, 0, stream>>>(x, dst_of_r, out_x, H, N); break;
        case 4: k_gatherT<4><<<N, TPB, 0, stream>>>(x, dst_of_r, out_x, H, N); break;
        default: k_gather_gen<<<N, TPB, 0, stream>>>(x, dst_of_r, out_x, H, N, K); break;
    }
}

// Round 8
// 75.343 us; speedup vs baseline: 2.6240x; 1.0302x over previous
//
#include <hip/hip_runtime.h>
#include <hip/hip_bf16.h>

#define TPB 256
#define NEXPERT 64

typedef float f32x4 __attribute__((ext_vector_type(4)));

// ---------------------------------------------------------------------------
// R8 = R2 structure with k_scan folded into k_scatter (3 dispatches, 2 gaps).
// Each scatter block bulk-loads the raw per-chunk counts (M = 64*NB ints,
// 16 KB) in one coalesced pass, exclusive-scans them in LDS, and proceeds
// with the byte-identical ballot rank. No serial dependent-load loops
// (the R3/R4/R6 failure mode).
// ---------------------------------------------------------------------------

// K1: per-chunk expert histogram. counts[e * NB + b] layout (raw counts).
__global__ void k_hist(const int* __restrict__ expert, int NK, int NB,
                       int* __restrict__ counts) {
    __shared__ int h[NEXPERT];
    const int b = blockIdx.x;
    for (int e = threadIdx.x; e < NEXPERT; e += blockDim.x) h[e] = 0;
    __syncthreads();
    const int i = b * TPB + threadIdx.x;
    if (i < NK) atomicAdd(&h[expert[i]], 1);
    __syncthreads();
    for (int e = threadIdx.x; e < NEXPERT; e += blockDim.x)
        counts[e * NB + b] = h[e];
}

// K2: stable scatter with in-block redundant scan + ballot rank.
__global__ __launch_bounds__(TPB) void k_scatter(
    const int* __restrict__ expert, const int* __restrict__ rowi,
    int NK, int NB, const int* __restrict__ counts,
    float* __restrict__ out_row, float* __restrict__ out_expert,
    int* __restrict__ dst_of_r) {
    extern __shared__ int lds[];             // [M] scanned counts | [TPB] s
    __shared__ int h[TPB / 64][NEXPERT + 1];
    const int M = NEXPERT * NB;
    int* cnt = lds;
    int* s = lds + M;
    const int b = blockIdx.x;
    const int tid = threadIdx.x;
    const int w = tid >> 6;
    const int lane = tid & 63;

    // ---- bulk-load raw counts (one coalesced pass, no serial round-trips)
    for (int j = tid; j < M; j += TPB) cnt[j] = counts[j];
    // zero the cross-wave rank table while loads are in flight
    for (int idx = tid; idx < (TPB / 64) * (NEXPERT + 1); idx += TPB)
        (&h[0][0])[idx] = 0;
    __syncthreads();

    // ---- exclusive scan of cnt[0..M) in LDS (ipt consecutive per thread)
    const int ipt = M / TPB;                 // 16 for the 8192x4096 shape
    const int base_i = tid * ipt;
    int sum = 0;
    for (int j = 0; j < ipt; ++j) sum += cnt[base_i + j];
    s[tid] = sum;
    __syncthreads();
    for (int off = 1; off < TPB; off <<= 1) {
        const int xv = (tid >= off) ? s[tid - off] : 0;
        __syncthreads();
        s[tid] += xv;
        __syncthreads();
    }
    int run = (tid == 0) ? 0 : s[tid - 1];
    for (int j = 0; j < ipt; ++j) {
        const int c = cnt[base_i + j];
        cnt[base_i + j] = run;
        run += c;
    }
    __syncthreads();

    // ---- ballot-based stable rank (byte-identical to R2) ----
    const int i = b * TPB + tid;
    const bool valid = (i < NK);
    const int e = valid ? expert[i] : NEXPERT;   // sentinel for inactive lanes

    unsigned long long mask = ~0ull;
#pragma unroll
    for (int bit = 0; bit < 7; ++bit) {
        const unsigned long long bv = __ballot((e >> bit) & 1);
        mask &= ((e >> bit) & 1) ? bv : ~bv;
    }
    const int rank_w = __popcll(mask & ((1ull << lane) - 1ull));
    const int cnt_w  = __popcll(mask);
    if (rank_w == 0) h[w][e] = cnt_w;   // lowest lane of each expert group
    __syncthreads();

    if (valid) {
        int rank = rank_w;
        for (int w2 = 0; w2 < w; ++w2) rank += h[w2][e];
        const int dst = cnt[e * NB + b] + rank;
        const int r = rowi[i];
        out_expert[dst] = (float)e;
        out_row[r] = (float)dst;
        dst_of_r[r] = dst;
    }
}

// K3: token-driven gather (byte-identical to R2's 77 µs winner).
template <int K>
__global__ void k_gatherT(const float* __restrict__ x,
                          const int* __restrict__ dst_of_r,
                          float* __restrict__ out_x, int H, int N) {
    const int t = blockIdx.x;
    const f32x4* __restrict__ src = (const f32x4*)(x + (size_t)t * (size_t)H);
    size_t ob[K];
#pragma unroll
    for (int kk = 0; kk < K; ++kk)
        ob[kk] = (size_t)dst_of_r[t + kk * N] * (size_t)H;
    const int n4 = H >> 2;
    for (int j = threadIdx.x; j < n4; j += blockDim.x) {
        const f32x4 v = src[j];
#pragma unroll
        for (int kk = 0; kk < K; ++kk)
            __builtin_nontemporal_store(v, (f32x4*)(out_x + ob[kk]) + j);
    }
}

// Generic-K fallback (only used for K > 4)
__global__ void k_gather_gen(const float* __restrict__ x,
                             const int* __restrict__ dst_of_r,
                             float* __restrict__ out_x, int H, int N, int K) {
    const int t = blockIdx.x;
    const f32x4* __restrict__ src = (const f32x4*)(x + (size_t)t * (size_t)H);
    const int n4 = H >> 2;
    for (int kk = 0; kk < K; ++kk) {
        const size_t ob = (size_t)dst_of_r[t + kk * N] * (size_t)H;
        for (int j = threadIdx.x; j < n4; j += blockDim.x)
            __builtin_nontemporal_store(src[j], (f32x4*)(out_x + ob) + j);
    }
}

extern "C" void kernel_launch(void* const* d_in, const int* in_sizes, int n_in,
                              void* d_out, int out_size, void* d_ws, size_t ws_size,
                              hipStream_t stream) {
    const float* x    = (const float*)d_in[0];  // [N, H] fp32
    const int*   rowi = (const int*)d_in[1];    // [N, K] int32 (arange)
    const int*   expi = (const int*)d_in[2];    // [N, K] int32

    const int NK = in_sizes[1];                    // N*K = 16384
    const int H  = (out_size - 2 * NK) / NK;       // 4096
    const int N  = in_sizes[0] / H;                // 8192
    const int K  = NK / N;                         // 2
    const int NB = (NK + TPB - 1) / TPB;           // 64 chunks

    // Output layout (all float32): [NK*H] expanded_x | [NK] row_idx | [NK] expert_idx
    float* out_x      = (float*)d_out;
    float* out_row    = out_x + (size_t)NK * (size_t)H;
    float* out_expert = out_row + NK;

    // Workspace: raw counts [64*NB] ints, then dst_of_r [NK] ints.
    int* counts   = (int*)d_ws;
    int* dst_of_r = counts + NEXPERT * NB;

    const int M = NEXPERT * NB;
    const size_t lds_bytes = (size_t)(M + TPB) * sizeof(int);

    k_hist   <<<NB, TPB, 0, stream>>>(expi, NK, NB, counts);
    k_scatter<<<NB, TPB, lds_bytes, stream>>>(expi, rowi, NK, NB, counts,
                                              out_row, out_expert, dst_of_r);

    switch (K) {
        case 1: k_gatherT<1><<<N, TPB, 0, stream>>>(x, dst_of_r, out_x, H, N); break;
        case 2: k_gatherT<2><<<N, TPB, 0, stream>>>(x, dst_of_r, out_x, H, N); break;
        case 3: k_gatherT<3><<<N, TPB, 0, stream>>>(x, dst_of_r, out_x, H, N); break;
        case 4: k_gatherT<4><<<N, TPB, 0, stream>>>(x, dst_of_r, out_x, H, N); break;
        default: k_gather_gen<<<N, TPB, 0, stream>>>(x, dst_of_r, out_x, H, N, K); break;
    }
}